// Round 5
// baseline (173.040 us; speedup 1.0000x reference)
//
#include <hip/hip_runtime.h>
#include <hip/hip_bf16.h>

typedef __bf16 bf16_t;
typedef __bf16 bf16x8 __attribute__((ext_vector_type(8)));
typedef float f32x4 __attribute__((ext_vector_type(4)));

static constexpr int NB  = 4096;  // batch
static constexpr int KIN = 768;   // D_IN
static constexpr int DD  = 256;   // D

// ---------------------------------------------------------------------------
// Kernel 1: pack W (KIN x DD, f32, k-major rows) -> Wt (DD x KIN, bf16)
// so the projection GEMM's B operand is K-contiguous per column.
// ---------------------------------------------------------------------------
__global__ __launch_bounds__(256) void pack_wt_kernel(
    const float* __restrict__ Wi, const float* __restrict__ Wx,
    bf16_t* __restrict__ Oi, bf16_t* __restrict__ Ox)
{
  int idx = blockIdx.x * 256 + threadIdx.x;
  const int half = DD * KIN;
  const float* W = (idx < half) ? Wi : Wx;
  bf16_t* O      = (idx < half) ? Oi : Ox;
  int j = (idx < half) ? idx : (idx - half);
  int k = j % KIN;
  int c = j / KIN;
  O[j] = (bf16_t)W[k * DD + c];
}

// ---------------------------------------------------------------------------
// Kernel 2: projection GEMM  F = X @ W + b   (4096 x 768 x 256), bf16 MFMA.
// blocks 0..63: images, 64..127: texts. 4 waves x 16 rows = 64 rows/block.
// Epilogue (from f32 accumulators): per-row 1/||f|| and strength dot (cs_w),
// and bf16 store of F for the big GEMM.
// ---------------------------------------------------------------------------
__global__ __launch_bounds__(256) void proj_kernel(
    const float* __restrict__ images, const float* __restrict__ texts,
    const bf16_t* __restrict__ Wti, const bf16_t* __restrict__ Wtt,
    const float* __restrict__ b_img, const float* __restrict__ b_txt,
    const float* __restrict__ cs_w,
    bf16_t* __restrict__ Fi, bf16_t* __restrict__ Ft,
    float* __restrict__ rni, float* __restrict__ si,
    float* __restrict__ rnt, float* __restrict__ st)
{
  const int bid = blockIdx.x;
  const bool isTxt = (bid >= 64);
  const float* X    = isTxt ? texts : images;
  const bf16_t* Wt  = isTxt ? Wtt : Wti;
  const float* bias = isTxt ? b_txt : b_img;
  const float* csw  = cs_w + (isTxt ? DD : 0);   // w2 for texts, w1 for images
  bf16_t* F     = isTxt ? Ft : Fi;
  float* rnorm  = isTxt ? rnt : rni;
  float* svec   = isTxt ? st : si;

  const int lane = threadIdx.x & 63;
  const int wave = threadIdx.x >> 6;
  const int lrow = lane & 15;
  const int g    = lane >> 4;
  const int rb   = (bid & 63) * 64 + wave * 16;   // wave's 16 rows

  const f32x4 fzero = {0.f, 0.f, 0.f, 0.f};
  f32x4 acc[16];
#pragma unroll
  for (int n = 0; n < 16; ++n) acc[n] = fzero;

  const float*  xp0 = X  + (size_t)(rb + lrow) * KIN + g * 8;
  const bf16_t* wp0 = Wt + (size_t)lrow * KIN + g * 8;

#pragma unroll 2
  for (int ks = 0; ks < KIN / 32; ++ks) {
    const float* xp = xp0 + ks * 32;
    f32x4 x0 = *reinterpret_cast<const f32x4*>(xp);
    f32x4 x1 = *reinterpret_cast<const f32x4*>(xp + 4);
    bf16x8 a;
#pragma unroll
    for (int e = 0; e < 4; ++e) { a[e] = (bf16_t)x0[e]; a[e + 4] = (bf16_t)x1[e]; }
#pragma unroll
    for (int n = 0; n < 16; ++n) {
      bf16x8 b = *reinterpret_cast<const bf16x8*>(wp0 + (size_t)n * 16 * KIN + ks * 32);
      acc[n] = __builtin_amdgcn_mfma_f32_16x16x32_bf16(a, b, acc[n], 0, 0, 0);
    }
  }

  // Epilogue: bias add, bf16 store, per-row norm^2 and strength dot.
  float nsq[4] = {0.f, 0.f, 0.f, 0.f};
  float sdt[4] = {0.f, 0.f, 0.f, 0.f};
#pragma unroll
  for (int n = 0; n < 16; ++n) {
    const int col = n * 16 + lrow;
    const float bn = bias[col];
    const float wn = csw[col];
#pragma unroll
    for (int r = 0; r < 4; ++r) {
      float v = acc[n][r] + bn;                   // row = rb + g*4 + r
      const int row = rb + g * 4 + r;
      F[(size_t)row * DD + col] = (bf16_t)v;
      nsq[r] += v * v;
      sdt[r] += v * wn;
    }
  }
  // Reduce across the 16 lanes of each g-group (xor masks < 16 stay in group).
#pragma unroll
  for (int msk = 8; msk >= 1; msk >>= 1) {
#pragma unroll
    for (int r = 0; r < 4; ++r) {
      nsq[r] += __shfl_xor(nsq[r], msk, 64);
      sdt[r] += __shfl_xor(sdt[r], msk, 64);
    }
  }
  if (lrow == 0) {
#pragma unroll
    for (int r = 0; r < 4; ++r) {
      const int row = rb + g * 4 + r;
      rnorm[row] = 1.0f / sqrtf(nsq[r]);
      svec[row]  = sdt[r];
    }
  }
}

// ---------------------------------------------------------------------------
// Kernel 3: sim = Fi @ Ft^T (4096 x 4096 x 256) + fused epilogue.
// 128x128 tile, 4 waves (2x2), each wave 64x64 = 4x4 MFMA fragments.
// Operands stay in L2 (4 MiB total); edge read + 3 output stores nontemporal.
// ---------------------------------------------------------------------------
__global__ __launch_bounds__(256) void sim_kernel(
    const bf16_t* __restrict__ Fi, const bf16_t* __restrict__ Ft,
    const float* __restrict__ rni, const float* __restrict__ si,
    const float* __restrict__ rnt, const float* __restrict__ st,
    const float* __restrict__ cs_b, const float* __restrict__ edge,
    float* __restrict__ out_final, float* __restrict__ out_sim,
    float* __restrict__ out_causal)
{
  // XCD-aware swizzle: 1024 blocks, 8 XCDs -> contiguous 128-block chunks.
  const int bid = blockIdx.x;
  const int swz = (bid & 7) * 128 + (bid >> 3);
  const int bx = swz & 31;   // col tile
  const int by = swz >> 5;   // row tile

  const int lane = threadIdx.x & 63;
  const int wave = threadIdx.x >> 6;
  const int wr = wave >> 1;
  const int wc = wave & 1;
  const int lrow = lane & 15;
  const int g    = lane >> 4;

  const int rowBase = by * 128 + wr * 64;
  const int colBase = bx * 128 + wc * 64;

  const f32x4 fzero = {0.f, 0.f, 0.f, 0.f};
  f32x4 acc[4][4];
#pragma unroll
  for (int m = 0; m < 4; ++m)
#pragma unroll
    for (int n = 0; n < 4; ++n) acc[m][n] = fzero;

  const bf16_t* ap0 = Fi + (size_t)(rowBase + lrow) * DD + g * 8;
  const bf16_t* bp0 = Ft + (size_t)(colBase + lrow) * DD + g * 8;

#pragma unroll 2
  for (int ks = 0; ks < DD / 32; ++ks) {
    bf16x8 a[4], b[4];
#pragma unroll
    for (int m = 0; m < 4; ++m)
      a[m] = *reinterpret_cast<const bf16x8*>(ap0 + (size_t)m * 16 * DD + ks * 32);
#pragma unroll
    for (int n = 0; n < 4; ++n)
      b[n] = *reinterpret_cast<const bf16x8*>(bp0 + (size_t)n * 16 * DD + ks * 32);
#pragma unroll
    for (int m = 0; m < 4; ++m)
#pragma unroll
      for (int n = 0; n < 4; ++n)
        acc[m][n] = __builtin_amdgcn_mfma_f32_16x16x32_bf16(a[m], b[n], acc[m][n], 0, 0, 0);
  }

  const float cb = cs_b[0];
  float rntv[4], stv[4];
#pragma unroll
  for (int n = 0; n < 4; ++n) {
    const int col = colBase + n * 16 + lrow;
    rntv[n] = rnt[col];
    stv[n]  = st[col];
  }

#pragma unroll
  for (int m = 0; m < 4; ++m) {
#pragma unroll
    for (int r = 0; r < 4; ++r) {
      const int row = rowBase + m * 16 + g * 4 + r;
      const float rn = rni[row];
      const float sv = si[row];
      const size_t rowOff = (size_t)row * NB;
#pragma unroll
      for (int n = 0; n < 4; ++n) {
        const int col = colBase + n * 16 + lrow;
        const size_t idx = rowOff + col;
        const float simv     = acc[m][n][r] * rn * rntv[n];
        const float strength = sv + stv[n] + cb;
        const float ew       = __builtin_nontemporal_load(edge + idx);
        const float causal   = ew * strength;
        const float fin      = simv + 0.3f * causal;
        __builtin_nontemporal_store(fin,    out_final  + idx);
        __builtin_nontemporal_store(simv,   out_sim    + idx);
        __builtin_nontemporal_store(causal, out_causal + idx);
      }
    }
  }
}

// ---------------------------------------------------------------------------
extern "C" void kernel_launch(void* const* d_in, const int* in_sizes, int n_in,
                              void* d_out, int out_size, void* d_ws, size_t ws_size,
                              hipStream_t stream) {
  const float* images = (const float*)d_in[0];
  const float* texts  = (const float*)d_in[1];
  const float* W_img  = (const float*)d_in[2];
  const float* b_img  = (const float*)d_in[3];
  const float* W_txt  = (const float*)d_in[4];
  const float* b_txt  = (const float*)d_in[5];
  const float* cs_w   = (const float*)d_in[6];
  const float* cs_b   = (const float*)d_in[7];
  const float* edge   = (const float*)d_in[8];

  float* out_final  = (float*)d_out;
  float* out_sim    = out_final + (size_t)NB * NB;
  float* out_causal = out_sim   + (size_t)NB * NB;

  // Workspace layout (~4.9 MiB total)
  char* ws = (char*)d_ws;
  bf16_t* Fi  = (bf16_t*)ws;                     // 4096*256 bf16
  bf16_t* Ft  = Fi  + (size_t)NB * DD;           // 4096*256 bf16
  bf16_t* Wti = Ft  + (size_t)NB * DD;           // 256*768 bf16
  bf16_t* Wtt = Wti + (size_t)DD * KIN;          // 256*768 bf16
  float*  rni = (float*)(Wtt + (size_t)DD * KIN);
  float*  siv = rni + NB;
  float*  rnt = siv + NB;
  float*  stv = rnt + NB;

  pack_wt_kernel<<<2 * DD * KIN / 256, 256, 0, stream>>>(W_img, W_txt, Wti, Wtt);
  proj_kernel<<<128, 256, 0, stream>>>(images, texts, Wti, Wtt, b_img, b_txt, cs_w,
                                       Fi, Ft, rni, siv, rnt, stv);
  sim_kernel<<<1024, 256, 0, stream>>>(Fi, Ft, rni, siv, rnt, stv, cs_b, edge,
                                       out_final, out_sim, out_causal);
}